// Round 2
// baseline (1711.563 us; speedup 1.0000x reference)
//
#include <hip/hip_runtime.h>
#include <cstdint>
#include <cstddef>

typedef unsigned short u16;
typedef __attribute__((ext_vector_type(8))) __bf16 bf16x8;
typedef __attribute__((ext_vector_type(4))) float f32x4;
typedef __attribute__((ext_vector_type(4))) unsigned int u32x4;

__device__ __forceinline__ float bf2f(u16 u){
  union { unsigned int i; float f; } x; x.i = ((unsigned int)u) << 16; return x.f;
}
__device__ __forceinline__ u16 f2bf(float f){
  union { float f; unsigned int i; } x; x.f = f;
  unsigned int i = x.i;
  return (u16)((i + 0x7fffu + ((i >> 16) & 1u)) >> 16);
}

// ---------------- K0: transpose+cast 5 weights (1024x1024 f32 -> bf16 W^T) ----------------
__global__ __launch_bounds__(256) void k_transpose(
    const float* __restrict__ wh, const float* __restrict__ ww,
    const float* __restrict__ wd, const float* __restrict__ wc,
    const float* __restrict__ wp, u16* __restrict__ wT)
{
  __shared__ u16 tile[32][33];
  const float* src = (blockIdx.z==0)?wh:(blockIdx.z==1)?ww:(blockIdx.z==2)?wd:(blockIdx.z==3)?wc:wp;
  u16* dst = wT + (size_t)blockIdx.z * 1048576;
  int x = blockIdx.x*32 + threadIdx.x;
  int y0 = blockIdx.y*32;
  for (int i = threadIdx.y; i < 32; i += 8)
    tile[i][threadIdx.x] = f2bf(src[(size_t)(y0+i)*1024 + x]);
  __syncthreads();
  int x2 = y0 + threadIdx.x;
  int y2 = blockIdx.x*32;
  for (int i = threadIdx.y; i < 32; i += 8)
    dst[(size_t)(y2+i)*1024 + x2] = tile[threadIdx.x][i];
}

// ---------------- K1: four branch GEMMs (h, w, d, c), f32 x -> bf16 staging ----------------
__global__ __launch_bounds__(256) void k_branch_gemm(
    const float* __restrict__ x, const u16* __restrict__ wT,
    const float* __restrict__ bh, const float* __restrict__ bw,
    const float* __restrict__ bd, const float* __restrict__ bc,
    u16* __restrict__ hbuf, u16* __restrict__ wbuf,
    u16* __restrict__ dbuf, u16* __restrict__ cbuf)
{
  const int branch = blockIdx.z;
  const int ntile  = blockIdx.x;   // 0..15
  const int rtile  = blockIdx.y;   // 0..511
  const int tid    = threadIdx.x;
  __shared__ __align__(16) u16 As[64][40];
  __shared__ __align__(16) u16 Bs[64][40];

  const u16* wsel = wT + (size_t)branch * 1048576;
  const float* bias = (branch==0)?bh:(branch==1)?bw:(branch==2)?bd:bc;
  u16* obuf         = (branch==0)?hbuf:(branch==1)?wbuf:(branch==2)?dbuf:cbuf;

  const int lrow = tid >> 2;        // 0..63
  const int lk8  = (tid & 3) * 8;   // 0,8,16,24
  const int r = rtile*64 + lrow;
  const int b = r >> 12, q1 = (r >> 8) & 15, q2 = (r >> 4) & 15, q3 = r & 15;

  size_t basea; int strideK;
  if      (branch == 0){ basea = ((size_t)b<<22) + (q2<<14) + (q3<<10) + (q1<<6); strideK = 262144; }
  else if (branch == 1){ basea = ((size_t)b<<22) + (q1<<18) + (q3<<10) + (q2<<6); strideK = 16384; }
  else if (branch == 2){ basea = ((size_t)b<<22) + (q1<<18) + (q2<<14) + (q3<<6); strideK = 1024; }
  else                 { basea = ((size_t)r<<10);                                 strideK = 64; }

  const int lane  = tid & 63;
  const int mbase = (tid >> 6) * 16;       // wave's 16-row strip
  const int fr    = lane & 15;             // frag row/col
  const int fq    = (lane >> 4) * 8;       // frag k offset
  f32x4 acc[4] = {};

  const u16* bsrc = wsel + (size_t)(ntile*64 + lrow) * 1024;

  for (int kt = 0; kt < 1024; kt += 32){
    int k0 = kt + lk8;
    const float* ap = x + basea + (size_t)(k0 >> 6)*strideK + (k0 & 63);
    f32x4 a0 = *(const f32x4*)(ap);
    f32x4 a1 = *(const f32x4*)(ap + 4);
    u32x4 bv = *(const u32x4*)(bsrc + k0);
    union { u32x4 v; u16 u[8]; } aw;
#pragma unroll
    for (int e = 0; e < 4; ++e){ aw.u[e] = f2bf(a0[e]); aw.u[e+4] = f2bf(a1[e]); }
    __syncthreads();
    *(u32x4*)(&As[lrow][lk8]) = aw.v;
    *(u32x4*)(&Bs[lrow][lk8]) = bv;
    __syncthreads();
    bf16x8 af = *(const bf16x8*)(&As[mbase + fr][fq]);
#pragma unroll
    for (int t = 0; t < 4; ++t){
      bf16x8 bfr = *(const bf16x8*)(&Bs[t*16 + fr][fq]);
      acc[t] = __builtin_amdgcn_mfma_f32_16x16x32_bf16(af, bfr, acc[t], 0, 0, 0);
    }
  }
#pragma unroll
  for (int t = 0; t < 4; ++t){
    int col = ntile*64 + t*16 + fr;
    float bv = bias[col];
#pragma unroll
    for (int rg = 0; rg < 4; ++rg){
      int row = rtile*64 + mbase + (lane >> 4)*4 + rg;
      obuf[(size_t)row*1024 + col] = f2bf(acc[t][rg] + bv);
    }
  }
}

// ---------------- K2: sum (h+w+d+c) over 4096 positions -> a_sum[b][c] (f32) ----------------
__global__ __launch_bounds__(256) void k_reduce(
    const u16* __restrict__ hbuf, const u16* __restrict__ wbuf,
    const u16* __restrict__ dbuf, const u16* __restrict__ cbuf,
    float* __restrict__ a_sum)
{
  const int b = blockIdx.x >> 4, sg = blockIdx.x & 15;
  const int s = threadIdx.x & 63, chunk = threadIdx.x >> 6;
  const size_t bb = (size_t)b << 22;
  float acc = 0.f;
  for (int h = chunk*4; h < chunk*4 + 4; ++h)
    for (int w = 0; w < 16; ++w)
      for (int d = 0; d < 16; ++d){
        acc += bf2f(hbuf[bb + (sg<<18) + (w<<14) + (d<<10) + (h<<6) + s]);
        acc += bf2f(wbuf[bb + (h<<18) + (sg<<14) + (d<<10) + (w<<6) + s]);
        acc += bf2f(dbuf[bb + (h<<18) + (w<<14) + (sg<<10) + (d<<6) + s]);
        acc += bf2f(cbuf[bb + (h<<18) + (w<<14) + (d<<10) + (sg<<6) + s]);
      }
  __shared__ float red[4][64];
  red[chunk][s] = acc;
  __syncthreads();
  if (chunk == 0)
    a_sum[b*1024 + (sg<<6) + s] = red[0][s] + red[1][s] + red[2][s] + red[3][s];
}

// ---------------- K3: MLP + per-channel softmax over the 4 branches (all f32) ----------------
__global__ __launch_bounds__(256) void k_mlp(
    const float* __restrict__ a_sum,
    const float* __restrict__ w1, const float* __restrict__ b1,
    const float* __restrict__ w2, const float* __restrict__ b2,
    float* __restrict__ alpha)
{
  const int b = blockIdx.x, tid = threadIdx.x;
  __shared__ float af[1024];
  __shared__ float z1[256];
  __shared__ float z2[4096];
  for (int i = tid; i < 1024; i += 256) af[i] = a_sum[b*1024 + i] * (1.0f/4096.0f);
  __syncthreads();
  {
    int j = tid;
    float acc = b1[j];
#pragma unroll 8
    for (int k = 0; k < 1024; ++k) acc += af[k] * w1[k*256 + j];
    z1[j] = 0.5f * acc * (1.0f + erff(acc * 0.70710678118654752f));
  }
  __syncthreads();
  for (int i = 0; i < 16; ++i){
    int j = tid + i*256;
    float acc = b2[j];
#pragma unroll 8
    for (int k = 0; k < 256; ++k) acc += z1[k] * w2[k*4096 + j];
    z2[j] = acc;
  }
  __syncthreads();
  for (int i = 0; i < 4; ++i){
    int c = tid + i*256;
    float v0 = z2[c*4+0], v1 = z2[c*4+1], v2 = z2[c*4+2], v3 = z2[c*4+3];
    float m = fmaxf(fmaxf(v0, v1), fmaxf(v2, v3));
    float e0 = expf(v0-m), e1 = expf(v1-m), e2 = expf(v2-m), e3 = expf(v3-m);
    float inv = 1.0f / (e0 + e1 + e2 + e3);
    alpha[0*8192 + b*1024 + c] = e0 * inv;
    alpha[1*8192 + b*1024 + c] = e1 * inv;
    alpha[2*8192 + b*1024 + c] = e2 * inv;
    alpha[3*8192 + b*1024 + c] = e3 * inv;
  }
}

// ---------------- K4a: mix = a0*h + a1*w + a2*d + a3*c -> bf16 mix buffer ----------------
__global__ __launch_bounds__(256) void k_mix(
    const u16* __restrict__ hbuf, const u16* __restrict__ wbuf,
    const u16* __restrict__ dbuf, const u16* __restrict__ cbuf,
    u16* __restrict__ mix, const float* __restrict__ alpha)
{
  int idx = blockIdx.x*256 + threadIdx.x;   // 0..4194303
  int p  = idx >> 7;
  int c0 = (idx & 127) << 3;
  int b = p >> 12, h = (p >> 8) & 15, w = (p >> 4) & 15, d = p & 15;
  int sg = c0 >> 6, s = c0 & 63;
  size_t bb = (size_t)b << 22;
  union { u32x4 v; u16 u[8]; } hv, wv, dv, cv, mv;
  hv.v = *(const u32x4*)(hbuf + bb + (sg<<18) + (w<<14) + (d<<10) + (h<<6) + s);
  wv.v = *(const u32x4*)(wbuf + bb + (h<<18) + (sg<<14) + (d<<10) + (w<<6) + s);
  dv.v = *(const u32x4*)(dbuf + bb + (h<<18) + (w<<14) + (sg<<10) + (d<<6) + s);
  cv.v = *(const u32x4*)(cbuf + ((size_t)p<<10) + c0);
  union { f32x4 f[2]; float a[8]; } a0, a1, a2, a3;
  const float* ab = alpha + b*1024 + c0;
  a0.f[0] = *(const f32x4*)(ab);         a0.f[1] = *(const f32x4*)(ab + 4);
  a1.f[0] = *(const f32x4*)(ab + 8192);  a1.f[1] = *(const f32x4*)(ab + 8196);
  a2.f[0] = *(const f32x4*)(ab + 16384); a2.f[1] = *(const f32x4*)(ab + 16388);
  a3.f[0] = *(const f32x4*)(ab + 24576); a3.f[1] = *(const f32x4*)(ab + 24580);
#pragma unroll
  for (int e = 0; e < 8; ++e){
    float m = a0.a[e]*bf2f(hv.u[e]) + a1.a[e]*bf2f(wv.u[e])
            + a2.a[e]*bf2f(dv.u[e]) + a3.a[e]*bf2f(cv.u[e]);
    mv.u[e] = f2bf(m);
  }
  *(u32x4*)(mix + ((size_t)p<<10) + c0) = mv.v;
}

// ---------------- K4b: out(f32) = mix(bf16) @ wp + bp ----------------
__global__ __launch_bounds__(256) void k_final_gemm(
    const u16* __restrict__ A, const u16* __restrict__ wpT,
    const float* __restrict__ bp, float* __restrict__ out)
{
  const int ntile = blockIdx.x, rtile = blockIdx.y;
  const int tid = threadIdx.x;
  __shared__ __align__(16) u16 As[64][40];
  __shared__ __align__(16) u16 Bs[64][40];
  const int lrow = tid >> 2, lk8 = (tid & 3) * 8;
  const int r = rtile*64 + lrow;
  const int lane = tid & 63;
  const int mbase = (tid >> 6) * 16;
  const int fr = lane & 15, fq = (lane >> 4) * 8;
  f32x4 acc[4] = {};
  const u16* asrc = A + ((size_t)r << 10);
  const u16* bsrc = wpT + (size_t)(ntile*64 + lrow) * 1024;

  for (int kt = 0; kt < 1024; kt += 32){
    int k0 = kt + lk8;
    u32x4 av = *(const u32x4*)(asrc + k0);
    u32x4 bv = *(const u32x4*)(bsrc + k0);
    __syncthreads();
    *(u32x4*)(&As[lrow][lk8]) = av;
    *(u32x4*)(&Bs[lrow][lk8]) = bv;
    __syncthreads();
    bf16x8 af = *(const bf16x8*)(&As[mbase + fr][fq]);
#pragma unroll
    for (int t = 0; t < 4; ++t){
      bf16x8 bfr = *(const bf16x8*)(&Bs[t*16 + fr][fq]);
      acc[t] = __builtin_amdgcn_mfma_f32_16x16x32_bf16(af, bfr, acc[t], 0, 0, 0);
    }
  }
#pragma unroll
  for (int t = 0; t < 4; ++t){
    int col = ntile*64 + t*16 + fr;
    float bv = bp[col];
#pragma unroll
    for (int rg = 0; rg < 4; ++rg){
      int row = rtile*64 + mbase + (lane >> 4)*4 + rg;
      out[(size_t)row*1024 + col] = acc[t][rg] + bv;
    }
  }
}

extern "C" void kernel_launch(void* const* d_in, const int* in_sizes, int n_in,
                              void* d_out, int out_size, void* d_ws, size_t ws_size,
                              hipStream_t stream)
{
  const float* x  = (const float*)d_in[0];
  const float* wh = (const float*)d_in[1];
  const float* bh = (const float*)d_in[2];
  const float* ww = (const float*)d_in[3];
  const float* bw = (const float*)d_in[4];
  const float* wd = (const float*)d_in[5];
  const float* bd = (const float*)d_in[6];
  const float* wc = (const float*)d_in[7];
  const float* bc = (const float*)d_in[8];
  const float* w1 = (const float*)d_in[9];
  const float* b1 = (const float*)d_in[10];
  const float* w2 = (const float*)d_in[11];
  const float* b2 = (const float*)d_in[12];
  const float* wp = (const float*)d_in[13];
  const float* bp = (const float*)d_in[14];
  char* ws = (char*)d_ws;

  // ws layout (~202.2 MiB):
  u16*   hbuf  = (u16*)(ws);                                  // 64 MiB bf16
  u16*   wbuf  = (u16*)(ws + 67108864);                       // 64 MiB bf16
  u16*   dbuf  = (u16*)(ws + 134217728);                      // 64 MiB bf16
  u16*   wT    = (u16*)(ws + 201326592);                      // 5 x 2 MiB bf16 W^T
  float* a_sum = (float*)(ws + 201326592 + 10485760);         // 32 KiB
  float* alpha = (float*)(ws + 201326592 + 10485760 + 32768); // 128 KiB
  // d_out (128 MiB f32 capacity) used as scratch: c (bf16) in bytes [0,64M),
  // mix (bf16) in bytes [64M,128M). Final f32 GEMM output goes into
  // ws[0,128M) (hbuf+wbuf dead by then), then d2d copy to d_out.
  u16*   cbuf  = (u16*)d_out;
  u16*   mix   = (u16*)d_out + 33554432;
  float* fout  = (float*)ws;

  k_transpose  <<<dim3(32, 32, 5),  dim3(32, 8), 0, stream>>>(wh, ww, wd, wc, wp, wT);
  k_branch_gemm<<<dim3(16, 512, 4), 256, 0, stream>>>(x, wT, bh, bw, bd, bc,
                                                      hbuf, wbuf, dbuf, cbuf);
  k_reduce     <<<dim3(128),        256, 0, stream>>>(hbuf, wbuf, dbuf, cbuf, a_sum);
  k_mlp        <<<dim3(8),          256, 0, stream>>>(a_sum, w1, b1, w2, b2, alpha);
  k_mix        <<<dim3(16384),      256, 0, stream>>>(hbuf, wbuf, dbuf, cbuf, mix, alpha);
  k_final_gemm <<<dim3(16, 512),    256, 0, stream>>>(mix, wT + 4*1048576, bp, fout);
  hipMemcpyAsync(d_out, fout, 134217728, hipMemcpyDeviceToDevice, stream);
  (void)in_sizes; (void)n_in; (void)out_size; (void)ws_size;
}